// Round 4
// baseline (188.868 us; speedup 1.0000x reference)
//
#include <hip/hip_runtime.h>
#include <hip/hip_bf16.h>
#include <math.h>

// TriangleAttention MI355X round 4.
// B=1, N=256, IN_DIM=128, H=4, D=32.
// k_prep: weights->bf16 (pair-bias weights pre-scaled by log2e), mask bitwords.
// k_proj: LN + qkv/pair/gate GEMM; qk staged in LDS for coalesced stores;
//         V stored j-bit-permuted (phi); gate stored transposed [c][p].
// k_attn: swapped-QK MFMA attention, softmax fully in-register (no max-sub,
//         exp2 domain), P->PV via register reinterpret (phi-matched V),
//         row-sum via ones-MFMA, fused gate + out-projection.
//
// ws layout (shorts unless noted):
//   qkb    [65536*256]        [p][q0..127 | k128..255]
//   Vtb    [4*256*32*256]     [h][r][d][phi(j)]
//   wT     [528*128]          proj weights [o][c] (qkv 0-383, gate 384-511, pair 512-515*log2e)
//   woT    [128*128]          w_out [o][c]
//   mjbg   u32[16]            mask bitwords per gr (2 words each)
//   pbf    f32[4*65536]       pair bias * log2e, [h][i*256+j]
//   gate_t f32[128*65536]     sigmoid gate, transposed [c][p]

#define NPOS 65536
#define LN_EPS 1e-5f
#define SCALE_L2E 0.25503487f        // (1/sqrt(32)) * log2(e)
#define MASKVAL  -1.4426950e-9f      // -1e-9 * log2(e)

typedef __attribute__((ext_vector_type(8))) short bf16x8;
typedef __attribute__((ext_vector_type(4))) float f32x4;

__device__ __forceinline__ short f2b(float f) {
    union { float f; unsigned u; } c; c.f = f;
    unsigned r = c.u + 0x7FFFu + ((c.u >> 16) & 1u);
    return (short)(r >> 16);
}
__device__ __forceinline__ unsigned cvt_pk(float lo, float hi) {
    unsigned r;
    asm("v_cvt_pk_bf16_f32 %0, %1, %2" : "=v"(r) : "v"(lo), "v"(hi));
    return r;
}

// ------------------------------------------------------------- weight prep
__global__ void k_prep(const float* __restrict__ wq, const float* __restrict__ wg,
                       const float* __restrict__ wp, const float* __restrict__ wo,
                       const int* __restrict__ smask,
                       short* __restrict__ wT, short* __restrict__ woT,
                       unsigned* __restrict__ mjbg)
{
    const int idx = blockIdx.x * 256 + threadIdx.x;
    const int stride = gridDim.x * 256;
    for (int i = idx; i < 528 * 128; i += stride) {
        const int o = i >> 7, c = i & 127;
        float v;
        if (o < 384)      v = wq[c * 384 + o];
        else if (o < 512) v = wg[c * 128 + (o - 384)];
        else if (o < 516) v = wp[c * 4 + (o - 512)] * 1.4426950408889634f;
        else              v = 0.f;
        wT[i] = f2b(v);
    }
    for (int i = idx; i < 128 * 128; i += stride) {
        const int o = i >> 7, c = i & 127;
        woT[i] = f2b(wo[c * 128 + o]);
    }
    if (blockIdx.x == 0 && threadIdx.x < 8) {
        const int gr = threadIdx.x >> 1, hw = threadIdx.x & 1;
        unsigned wbits = 0;
        for (int b = 0; b < 32; ++b) {
            const int k = hw * 32 + b;                    // k = nt*4 + reg
            const int j = (k >> 2) * 16 + gr * 4 + (k & 3);
            if (smask[j] == 0) wbits |= (1u << b);
        }
        mjbg[threadIdx.x] = wbits;
    }
}

// ------------------------------------------------------------- LN + projections
__global__ __launch_bounds__(256) void k_proj(
    const float* __restrict__ z, const float* __restrict__ ln_g,
    const float* __restrict__ ln_b, const short* __restrict__ wT,
    const float* __restrict__ b_gate, short* __restrict__ qkb,
    short* __restrict__ Vtb, float* __restrict__ pbf, float* __restrict__ gate_t)
{
    __shared__ short sBuf[64 * 264];   // LN zn (cols 0-127), then qk tile (cols 0-255)
    const int t = threadIdx.x, w = t >> 6, l = t & 63;
    const int lg = l & 15, gr = l >> 4;
    const int p0 = blockIdx.x * 64;
    const f32x4 zero4 = {0.f, 0.f, 0.f, 0.f};

    // --- LayerNorm: 4 threads per row, 32 channels each
    {
        const int row = t >> 2, q = t & 3;
        const float* zr = z + (size_t)(p0 + row) * 128 + q * 32;
        float v[32];
        float s = 0.f, sq = 0.f;
#pragma unroll
        for (int u = 0; u < 8; ++u) {
            const float4 f = ((const float4*)zr)[u];
            v[u * 4 + 0] = f.x; v[u * 4 + 1] = f.y;
            v[u * 4 + 2] = f.z; v[u * 4 + 3] = f.w;
            s += f.x + f.y + f.z + f.w;
            sq += f.x * f.x + f.y * f.y + f.z * f.z + f.w * f.w;
        }
        s  += __shfl_xor(s, 1, 4);  s  += __shfl_xor(s, 2, 4);
        sq += __shfl_xor(sq, 1, 4); sq += __shfl_xor(sq, 2, 4);
        const float mu = s * (1.f / 128.f);
        const float rstd = rsqrtf(sq * (1.f / 128.f) - mu * mu + LN_EPS);
        short tmp[32];
#pragma unroll
        for (int u = 0; u < 32; ++u) {
            const int c = q * 32 + u;
            tmp[u] = f2b((v[u] - mu) * rstd * ln_g[c] + ln_b[c]);
        }
        uint4* dst = (uint4*)(sBuf + row * 264 + q * 32);
#pragma unroll
        for (int u = 0; u < 4; ++u) dst[u] = *(uint4*)&tmp[u * 8];
    }
    __syncthreads();

    bf16x8 a[4][4];
#pragma unroll
    for (int mt = 0; mt < 4; ++mt)
#pragma unroll
        for (int kc = 0; kc < 4; ++kc)
            a[mt][kc] = *(const bf16x8*)(sBuf + (mt * 16 + lg) * 264 + kc * 32 + gr * 8);
    __syncthreads();   // frags in regs; sBuf reusable for qk staging

    for (int nt = w; nt < 33; nt += 4) {
        bf16x8 bfr[4];
#pragma unroll
        for (int kc = 0; kc < 4; ++kc)
            bfr[kc] = *(const bf16x8*)(wT + (size_t)(nt * 16 + lg) * 128 + kc * 32 + gr * 8);
        const int o = nt * 16 + lg;
#pragma unroll
        for (int mt = 0; mt < 4; ++mt) {
            f32x4 acc = zero4;
#pragma unroll
            for (int kc = 0; kc < 4; ++kc)
                acc = __builtin_amdgcn_mfma_f32_16x16x32_bf16(a[mt][kc], bfr[kc], acc, 0, 0, 0);
            const int pr = p0 + mt * 16 + gr * 4;
            if (o < 256) {
#pragma unroll
                for (int reg = 0; reg < 4; ++reg)
                    sBuf[(mt * 16 + gr * 4 + reg) * 264 + o] = f2b(acc[reg]);
            } else if (o < 384) {
                const int hh = (o - 256) >> 5, d = (o - 256) & 31;
                const int r = pr >> 8, jb = pr & 255;
                const int jphi = (jb & 0xE0) | ((jb & 12) << 1) | ((jb >> 2) & 4);
                union { unsigned long long u; short sh[4]; } pk;
#pragma unroll
                for (int reg = 0; reg < 4; ++reg) pk.sh[reg] = f2b(acc[reg]);
                *(unsigned long long*)(Vtb + (((size_t)hh * 256 + r) * 32 + d) * 256 + jphi) = pk.u;
            } else if (o < 512) {
                const float bg = b_gate[o - 384];
                f32x4 gv;
#pragma unroll
                for (int reg = 0; reg < 4; ++reg)
                    gv[reg] = 1.f / (1.f + __expf(-(acc[reg] + bg)));
                *(f32x4*)(gate_t + (size_t)(o - 384) * NPOS + pr) = gv;
            } else if (o < 516) {
                *(f32x4*)(pbf + (size_t)(o - 512) * NPOS + pr) = acc;
            }
        }
    }
    __syncthreads();

    // coalesced qkb write-out: 4 threads per row, 128B each
    {
        const int row = t >> 2, seg = t & 3;
        const short* src = sBuf + row * 264 + seg * 64;
        short* dst = qkb + (size_t)(p0 + row) * 256 + seg * 64;
#pragma unroll
        for (int u = 0; u < 8; ++u)
            *(uint4*)(dst + u * 8) = *(const uint4*)(src + u * 8);
    }
}

// ------------------------------------------------------------- attention + out-proj
// block = (r, oct of 32 i); wave = head. No LDS, no shuffles in main loop.
__global__ __launch_bounds__(256, 3) void k_attn(
    const short* __restrict__ qkb, const short* __restrict__ Vtb,
    const float* __restrict__ pbf, const int* __restrict__ smask,
    const float* __restrict__ gate_t, const unsigned* __restrict__ mjbg,
    const short* __restrict__ woT, const float* __restrict__ b_out,
    float* __restrict__ out)
{
    __shared__ short sX[32 * 136];   // gated attn output, bf16
    const int t = threadIdx.x, h = t >> 6, l = t & 63;
    const int lg = l & 15, gr = l >> 4;
    const int r = blockIdx.x >> 3, oct = blockIdx.x & 7;
    const int rb = r * 256;
    const f32x4 zero4 = {0.f, 0.f, 0.f, 0.f};
    const size_t vbase = ((size_t)h * 256 + r) * 8192;
    const unsigned long long mjb = ((const unsigned long long*)mjbg)[gr];
    bf16x8 ones;
#pragma unroll
    for (int u = 0; u < 8; ++u) ones[u] = (short)0x3F80;

    for (int tile = 0; tile < 2; ++tile) {
        const int i0 = oct * 32 + tile * 16;
        const bf16x8 qf = *(const bf16x8*)(qkb + (size_t)(rb + i0 + lg) * 256 + h * 32 + gr * 8);

        // QK^T (swapped): lane holds S[j = nt*16 + gr*4 + reg][i = i0+lg]
        f32x4 accS[16];
#pragma unroll
        for (int nt = 0; nt < 16; ++nt) {
            const bf16x8 kf = *(const bf16x8*)(qkb + (size_t)(rb + nt * 16 + lg) * 256 + 128 + h * 32 + gr * 8);
            accS[nt] = __builtin_amdgcn_mfma_f32_16x16x32_bf16(kf, qf, zero4, 0, 0, 0);
        }

        const bool bi = smask[i0 + lg] == 0;

        // bias + mask + exp2 (no max-sub; softmax shift-invariant) + pack
        unsigned pk[32];
#pragma unroll
        for (int nt = 0; nt < 16; ++nt) {
            const f32x4 pbv = *(const f32x4*)(pbf + (size_t)h * NPOS + (size_t)(i0 + lg) * 256 + nt * 16 + gr * 4);
            float pv[4];
#pragma unroll
            for (int reg = 0; reg < 4; ++reg) {
                const bool bj = (mjb >> (nt * 4 + reg)) & 1;
                float lv = fmaf(accS[nt][reg], SCALE_L2E, pbv[reg]);
                lv = (bi != bj) ? MASKVAL : lv;
                pv[reg] = exp2f(lv);
            }
            pk[nt * 2 + 0] = cvt_pk(pv[0], pv[1]);
            pk[nt * 2 + 1] = cvt_pk(pv[2], pv[3]);
        }

        // PV + row-sum: pa = 4 consecutive pk u32s (phi-matched V layout)
        f32x4 o0 = zero4, o1 = zero4, o2 = zero4;
#pragma unroll
        for (int kc = 0; kc < 8; ++kc) {
            const bf16x8 pa = *(const bf16x8*)(&pk[kc * 4]);
            const bf16x8 v0 = *(const bf16x8*)(Vtb + vbase + (size_t)lg * 256 + kc * 32 + gr * 8);
            const bf16x8 v1 = *(const bf16x8*)(Vtb + vbase + (size_t)(lg + 16) * 256 + kc * 32 + gr * 8);
            o0 = __builtin_amdgcn_mfma_f32_16x16x32_bf16(pa, v0, o0, 0, 0, 0);
            o1 = __builtin_amdgcn_mfma_f32_16x16x32_bf16(pa, v1, o1, 0, 0, 0);
            o2 = __builtin_amdgcn_mfma_f32_16x16x32_bf16(pa, ones, o2, 0, 0, 0);
        }

        // epilogue: normalize by row-sum, gate, stash bf16
        const int prow0 = rb + i0 + gr * 4;
        const f32x4 g0 = *(const f32x4*)(gate_t + (size_t)(h * 32 + lg) * NPOS + prow0);
        const f32x4 g1 = *(const f32x4*)(gate_t + (size_t)(h * 32 + 16 + lg) * NPOS + prow0);
#pragma unroll
        for (int reg = 0; reg < 4; ++reg) {
            const float inv = 1.f / o2[reg];
            const int lr = tile * 16 + gr * 4 + reg;
            sX[lr * 136 + h * 32 + lg]      = f2b(o0[reg] * inv * g0[reg]);
            sX[lr * 136 + h * 32 + 16 + lg] = f2b(o1[reg] * inv * g1[reg]);
        }
    }
    __syncthreads();

    // --- out-projection: wave w -> rows (w&1)*16.., o-half (w>>1)
    {
        const int rw = (h & 1) * 16, oh = h >> 1;
        bf16x8 ax[4];
#pragma unroll
        for (int kc = 0; kc < 4; ++kc)
            ax[kc] = *(const bf16x8*)(sX + (rw + lg) * 136 + kc * 32 + gr * 8);
        const int pb16 = rb + oct * 32 + rw;
        for (int nt = 0; nt < 4; ++nt) {
            const int o = oh * 64 + nt * 16 + lg;
            bf16x8 bw[4];
#pragma unroll
            for (int kc = 0; kc < 4; ++kc)
                bw[kc] = *(const bf16x8*)(woT + (size_t)o * 128 + kc * 32 + gr * 8);
            f32x4 c = zero4;
#pragma unroll
            for (int kc = 0; kc < 4; ++kc)
                c = __builtin_amdgcn_mfma_f32_16x16x32_bf16(ax[kc], bw[kc], c, 0, 0, 0);
            const float bo = b_out[o];
#pragma unroll
            for (int reg = 0; reg < 4; ++reg)
                out[(size_t)(pb16 + gr * 4 + reg) * 128 + o] = c[reg] + bo;
        }
    }
}

// ------------------------------------------------------------- launch
extern "C" void kernel_launch(void* const* d_in, const int* in_sizes, int n_in,
                              void* d_out, int out_size, void* d_ws, size_t ws_size,
                              hipStream_t stream)
{
    const float* z      = (const float*)d_in[0];
    const int*   smask  = (const int*)d_in[1];
    const float* ln_g   = (const float*)d_in[2];
    const float* ln_b   = (const float*)d_in[3];
    const float* w_qkv  = (const float*)d_in[4];
    const float* w_pair = (const float*)d_in[5];
    const float* w_gate = (const float*)d_in[6];
    const float* b_gate = (const float*)d_in[7];
    const float* w_out  = (const float*)d_in[8];
    const float* b_out  = (const float*)d_in[9];
    float* out = (float*)d_out;

    short* ws      = (short*)d_ws;
    short* qkb     = ws;                                   // 65536*256
    short* Vtb     = qkb + (size_t)NPOS * 256;             // 8388608
    short* wT      = Vtb + (size_t)8388608;                // 528*128
    short* woT     = wT + 528 * 128;                       // 128*128
    unsigned* mjbg = (unsigned*)(woT + 128 * 128);         // 16 u32 (8 used)
    float* pbf     = (float*)(mjbg + 16);                  // 4*65536
    float* gate_t  = pbf + (size_t)4 * NPOS;               // 128*65536

    k_prep<<<64, 256, 0, stream>>>(w_qkv, w_gate, w_pair, w_out, smask, wT, woT, mjbg);
    k_proj<<<NPOS / 64, 256, 0, stream>>>(z, ln_g, ln_b, wT, b_gate, qkb, Vtb, pbf, gate_t);
    k_attn<<<2048, 256, 0, stream>>>(qkb, Vtb, pbf, smask, gate_t, mjbg, woT, b_out, out);
}

// Round 5
// 136.493 us; speedup vs baseline: 1.3837x; 1.3837x over previous
//
#include <hip/hip_runtime.h>
#include <hip/hip_bf16.h>
#include <math.h>

// TriangleAttention MI355X round 5.
// B=1, N=256, IN_DIM=128, H=4, D=32.
// k_prep: weights->bf16 (pair weights pre-scaled by log2e), mask bitwords.
// k_proj: LN + GEMM in two passes over one LDS buffer:
//         pass A: qk cols -> staged -> coalesced qkb write
//         pass B: V (phi-permuted j), gate (sigmoid, bf16), pb (bf16) -> staged -> coalesced writes
// k_attn: block=(r,half), wave=head, kf hoisted in VGPRs; swapped-QK MFMA,
//         in-register exp2 softmax (no max-sub), P->PV register reinterpret
//         (phi-matched V), ones-MFMA row-sum, fused gate + out-projection
//         through XOR-swizzled sX.
//
// ws: qkb short[65536*256], Vtb short[4*256*32*256] ([h][r][d][phi(j)]),
//     wT short[528*128], woT short[128*128], mjbg u32[16],
//     pbb short[4*65536] (bf16, *log2e), gate_b short[65536*128] (bf16 [p][c])

#define NPOS 65536
#define LN_EPS 1e-5f
#define SCALE_L2E 0.25503487f        // (1/sqrt(32)) * log2(e)
#define MASKVAL  -1.4426950e-9f      // -1e-9 * log2(e)

typedef __attribute__((ext_vector_type(8))) short bf16x8;
typedef __attribute__((ext_vector_type(4))) float f32x4;

__device__ __forceinline__ short f2b(float f) {
    union { float f; unsigned u; } c; c.f = f;
    unsigned r = c.u + 0x7FFFu + ((c.u >> 16) & 1u);
    return (short)(r >> 16);
}
__device__ __forceinline__ unsigned cvt_pk(float lo, float hi) {
    unsigned r;
    asm("v_cvt_pk_bf16_f32 %0, %1, %2" : "=v"(r) : "v"(lo), "v"(hi));
    return r;
}
__device__ __forceinline__ float b2f_lo(unsigned u) {
    union { unsigned u; float f; } c; c.u = u << 16; return c.f;
}
__device__ __forceinline__ float b2f_hi(unsigned u) {
    union { unsigned u; float f; } c; c.u = u & 0xFFFF0000u; return c.f;
}

// ------------------------------------------------------------- weight prep
__global__ void k_prep(const float* __restrict__ wq, const float* __restrict__ wg,
                       const float* __restrict__ wp, const float* __restrict__ wo,
                       const int* __restrict__ smask,
                       short* __restrict__ wT, short* __restrict__ woT,
                       unsigned* __restrict__ mjbg)
{
    const int idx = blockIdx.x * 256 + threadIdx.x;
    const int stride = gridDim.x * 256;
    for (int i = idx; i < 528 * 128; i += stride) {
        const int o = i >> 7, c = i & 127;
        float v;
        if (o < 384)      v = wq[c * 384 + o];
        else if (o < 512) v = wg[c * 128 + (o - 384)];
        else if (o < 516) v = wp[c * 4 + (o - 512)] * 1.4426950408889634f;
        else              v = 0.f;
        wT[i] = f2b(v);
    }
    for (int i = idx; i < 128 * 128; i += stride) {
        const int o = i >> 7, c = i & 127;
        woT[i] = f2b(wo[c * 128 + o]);
    }
    if (blockIdx.x == 0 && threadIdx.x < 8) {
        const int gr = threadIdx.x >> 1, hw = threadIdx.x & 1;
        unsigned wbits = 0;
        for (int b = 0; b < 32; ++b) {
            const int k = hw * 32 + b;                    // k = nt*4 + reg
            const int j = (k >> 2) * 16 + gr * 4 + (k & 3);
            if (smask[j] == 0) wbits |= (1u << b);
        }
        mjbg[threadIdx.x] = wbits;
    }
}

// ------------------------------------------------------------- LN + projections
// 64 positions per block (one r, j-range p0&255 .. +63).
__global__ __launch_bounds__(256) void k_proj(
    const float* __restrict__ z, const float* __restrict__ ln_g,
    const float* __restrict__ ln_b, const short* __restrict__ wT,
    const float* __restrict__ b_gate, short* __restrict__ qkb,
    short* __restrict__ Vtb, short* __restrict__ pbb, short* __restrict__ gate_b)
{
    __shared__ short sBuf[17920];   // phase1: [64][264] LN/qk; phase2: V [128][72] + gate [64][136]
    const int t = threadIdx.x, w = t >> 6, l = t & 63;
    const int lg = l & 15, gr = l >> 4;
    const int p0 = blockIdx.x * 64;
    const f32x4 zero4 = {0.f, 0.f, 0.f, 0.f};
    short* sV = sBuf;           // [128][72]
    short* sG = sBuf + 9216;    // [64][136]

    // --- LayerNorm: 4 threads per row, 32 channels each -> sBuf [64][264]
    {
        const int row = t >> 2, q = t & 3;
        const float* zr = z + (size_t)(p0 + row) * 128 + q * 32;
        float v[32];
        float s = 0.f, sq = 0.f;
#pragma unroll
        for (int u = 0; u < 8; ++u) {
            const float4 f = ((const float4*)zr)[u];
            v[u * 4 + 0] = f.x; v[u * 4 + 1] = f.y;
            v[u * 4 + 2] = f.z; v[u * 4 + 3] = f.w;
            s += f.x + f.y + f.z + f.w;
            sq += f.x * f.x + f.y * f.y + f.z * f.z + f.w * f.w;
        }
        s  += __shfl_xor(s, 1, 4);  s  += __shfl_xor(s, 2, 4);
        sq += __shfl_xor(sq, 1, 4); sq += __shfl_xor(sq, 2, 4);
        const float mu = s * (1.f / 128.f);
        const float rstd = rsqrtf(sq * (1.f / 128.f) - mu * mu + LN_EPS);
        short tmp[32];
#pragma unroll
        for (int u = 0; u < 32; ++u) {
            const int c = q * 32 + u;
            tmp[u] = f2b((v[u] - mu) * rstd * ln_g[c] + ln_b[c]);
        }
        uint4* dst = (uint4*)(sBuf + row * 264 + q * 32);
#pragma unroll
        for (int u = 0; u < 4; ++u) dst[u] = *(uint4*)&tmp[u * 8];
    }
    __syncthreads();

    bf16x8 a[4][4];
#pragma unroll
    for (int mt = 0; mt < 4; ++mt)
#pragma unroll
        for (int kc = 0; kc < 4; ++kc)
            a[mt][kc] = *(const bf16x8*)(sBuf + (mt * 16 + lg) * 264 + kc * 32 + gr * 8);
    __syncthreads();

    // --- pass A: qk columns (o < 256), staged in sBuf [64][264]
    for (int nt = w; nt < 16; nt += 4) {
        bf16x8 bfr[4];
#pragma unroll
        for (int kc = 0; kc < 4; ++kc)
            bfr[kc] = *(const bf16x8*)(wT + (size_t)(nt * 16 + lg) * 128 + kc * 32 + gr * 8);
        const int o = nt * 16 + lg;
#pragma unroll
        for (int mt = 0; mt < 4; ++mt) {
            f32x4 acc = zero4;
#pragma unroll
            for (int kc = 0; kc < 4; ++kc)
                acc = __builtin_amdgcn_mfma_f32_16x16x32_bf16(a[mt][kc], bfr[kc], acc, 0, 0, 0);
#pragma unroll
            for (int reg = 0; reg < 4; ++reg)
                sBuf[(mt * 16 + gr * 4 + reg) * 264 + o] = f2b(acc[reg]);
        }
    }
    __syncthreads();
    // coalesced qkb write-out: 4 threads per row, 128B each
    {
        const int row = t >> 2, seg = t & 3;
        const short* src = sBuf + row * 264 + seg * 64;
        short* dst = qkb + (size_t)(p0 + row) * 256 + seg * 64;
#pragma unroll
        for (int u = 0; u < 8; ++u)
            *(uint4*)(dst + u * 8) = *(const uint4*)(src + u * 8);
    }
    __syncthreads();

    // --- pass B: V (o 256-383), gate (384-511), pb (512-515)
    for (int nt = 16 + w; nt < 33; nt += 4) {
        bf16x8 bfr[4];
#pragma unroll
        for (int kc = 0; kc < 4; ++kc)
            bfr[kc] = *(const bf16x8*)(wT + (size_t)(nt * 16 + lg) * 128 + kc * 32 + gr * 8);
        const int o = nt * 16 + lg;
#pragma unroll
        for (int mt = 0; mt < 4; ++mt) {
            f32x4 acc = zero4;
#pragma unroll
            for (int kc = 0; kc < 4; ++kc)
                acc = __builtin_amdgcn_mfma_f32_16x16x32_bf16(a[mt][kc], bfr[kc], acc, 0, 0, 0);
            const int pr = p0 + mt * 16 + gr * 4;
            if (o < 384) {
                const int row = o - 256;                    // hh*32 + d
                const int jl = mt * 16 + gr * 4;            // local j, 4-aligned
                const int jp = (jl & 0x23) | ((jl & 12) << 1) | ((jl >> 2) & 4);
                union { unsigned long long u; short sh[4]; } pk;
#pragma unroll
                for (int reg = 0; reg < 4; ++reg) pk.sh[reg] = f2b(acc[reg]);
                *(unsigned long long*)(sV + row * 72 + jp) = pk.u;
            } else if (o < 512) {
                const int c = o - 384;
                const float bg = b_gate[c];
#pragma unroll
                for (int reg = 0; reg < 4; ++reg)
                    sG[(mt * 16 + gr * 4 + reg) * 136 + c] =
                        f2b(1.f / (1.f + __expf(-(acc[reg] + bg))));
            } else if (o < 516) {
                union { unsigned long long u; short sh[4]; } pk;
#pragma unroll
                for (int reg = 0; reg < 4; ++reg) pk.sh[reg] = f2b(acc[reg]);
                *(unsigned long long*)(pbb + (size_t)(o - 512) * NPOS + pr) = pk.u;
            }
        }
    }
    __syncthreads();

    // coalesced write-out: V rows (h,d) 64B per thread; gate rows 64B per thread
    {
        const int r = p0 >> 8, jbase = p0 & 255;
        const int row = t >> 1, half = t & 1;               // V: 128 rows x 2
        const short* src = sV + row * 72 + half * 32;
        const int hh = row >> 5, d = row & 31;
        short* dst = Vtb + (((size_t)hh * 256 + r) * 32 + d) * 256 + jbase + half * 32;
#pragma unroll
        for (int u = 0; u < 4; ++u)
            *(uint4*)(dst + u * 8) = *(const uint4*)(src + u * 8);

        const int grow = t >> 2, q = t & 3;                 // gate: 64 rows x 4
        const short* gsrc = sG + grow * 136 + q * 32;
        short* gdst = gate_b + (size_t)(p0 + grow) * 128 + q * 32;
#pragma unroll
        for (int u = 0; u < 4; ++u)
            *(uint4*)(gdst + u * 8) = *(const uint4*)(gsrc + u * 8);
    }
}

// ------------------------------------------------------------- attention + out-proj
// block = (r, ihalf); wave = head; 8 i-tiles of 16. K hoisted in VGPRs.
__global__ __launch_bounds__(256, 2) void k_attn(
    const short* __restrict__ qkb, const short* __restrict__ Vtb,
    const short* __restrict__ pbb, const int* __restrict__ smask,
    const short* __restrict__ gate_b, const unsigned* __restrict__ mjbg,
    const short* __restrict__ woT, const float* __restrict__ b_out,
    float* __restrict__ out)
{
    __shared__ short sX[128 * 128];   // gated attn output, bf16, XOR-swizzled units
    const int t = threadIdx.x, h = t >> 6, l = t & 63;
    const int lg = l & 15, gr = l >> 4;
    const int r = blockIdx.x >> 1, ihalf = blockIdx.x & 1;
    const int rb = r * 256;
    const f32x4 zero4 = {0.f, 0.f, 0.f, 0.f};
    const size_t vbase = ((size_t)h * 256 + r) * 8192;
    const unsigned long long mjb = ((const unsigned long long*)mjbg)[gr];
    bf16x8 ones;
#pragma unroll
    for (int u = 0; u < 8; ++u) ones[u] = (short)0x3F80;

    // hoist K fragments for (r, h): 64 VGPRs, read once
    bf16x8 kf[16];
#pragma unroll
    for (int nt = 0; nt < 16; ++nt)
        kf[nt] = *(const bf16x8*)(qkb + (size_t)(rb + nt * 16 + lg) * 256 + 128 + h * 32 + gr * 8);

    for (int mtl = 0; mtl < 8; ++mtl) {
        const int i0 = ihalf * 128 + mtl * 16;
        // issue all tile loads up front (Q first; QK's waitcnt covers only Q)
        const bf16x8 qf = *(const bf16x8*)(qkb + (size_t)(rb + i0 + lg) * 256 + h * 32 + gr * 8);
        uint2 pbp[16];
#pragma unroll
        for (int nt = 0; nt < 16; ++nt)
            pbp[nt] = *(const uint2*)(pbb + (size_t)h * NPOS + (size_t)(i0 + lg) * 256 + nt * 16 + gr * 4);
        unsigned short gu0[4], gu1[4];
        {
            const int prow0 = rb + i0 + gr * 4;
#pragma unroll
            for (int reg = 0; reg < 4; ++reg) {
                gu0[reg] = *(const unsigned short*)(gate_b + (size_t)(prow0 + reg) * 128 + h * 32 + lg);
                gu1[reg] = *(const unsigned short*)(gate_b + (size_t)(prow0 + reg) * 128 + h * 32 + 16 + lg);
            }
        }
        const bool bi = smask[i0 + lg] == 0;

        // QK^T (swapped): lane holds S[j = nt*16 + gr*4 + reg][i = i0+lg]
        f32x4 accS[16];
#pragma unroll
        for (int nt = 0; nt < 16; ++nt)
            accS[nt] = __builtin_amdgcn_mfma_f32_16x16x32_bf16(kf[nt], qf, zero4, 0, 0, 0);

        // bias + mask + exp2 (shift-invariant softmax, no max-sub) + pack
        unsigned pk[32];
#pragma unroll
        for (int nt = 0; nt < 16; ++nt) {
            const unsigned px = pbp[nt].x, py = pbp[nt].y;
            float pbv[4] = { b2f_lo(px), b2f_hi(px), b2f_lo(py), b2f_hi(py) };
            float pv[4];
#pragma unroll
            for (int reg = 0; reg < 4; ++reg) {
                const bool bj = (mjb >> (nt * 4 + reg)) & 1;
                float lv = fmaf(accS[nt][reg], SCALE_L2E, pbv[reg]);
                lv = (bi != bj) ? MASKVAL : lv;
                pv[reg] = exp2f(lv);
            }
            pk[nt * 2 + 0] = cvt_pk(pv[0], pv[1]);
            pk[nt * 2 + 1] = cvt_pk(pv[2], pv[3]);
        }

        // PV + row-sum (phi-matched V layout; pa = 4 consecutive pk words)
        f32x4 o0 = zero4, o1 = zero4, o2 = zero4;
#pragma unroll
        for (int kc = 0; kc < 8; ++kc) {
            const bf16x8 pa = *(const bf16x8*)(&pk[kc * 4]);
            const bf16x8 v0 = *(const bf16x8*)(Vtb + vbase + (size_t)lg * 256 + kc * 32 + gr * 8);
            const bf16x8 v1 = *(const bf16x8*)(Vtb + vbase + (size_t)(lg + 16) * 256 + kc * 32 + gr * 8);
            o0 = __builtin_amdgcn_mfma_f32_16x16x32_bf16(pa, v0, o0, 0, 0, 0);
            o1 = __builtin_amdgcn_mfma_f32_16x16x32_bf16(pa, v1, o1, 0, 0, 0);
            o2 = __builtin_amdgcn_mfma_f32_16x16x32_bf16(pa, ones, o2, 0, 0, 0);
        }

        // epilogue: normalize, gate, stash bf16 into swizzled sX
#pragma unroll
        for (int reg = 0; reg < 4; ++reg) {
            const float inv = 1.f / o2[reg];
            const int lr = mtl * 16 + gr * 4 + reg;
            const float g0 = b2f_lo((unsigned)gu0[reg]);
            const float g1 = b2f_lo((unsigned)gu1[reg]);
            const int u0 = (h * 4 + (lg >> 3)) ^ (lr & 7);
            const int u1 = (h * 4 + 2 + (lg >> 3)) ^ (lr & 7);
            sX[lr * 128 + u0 * 8 + (lg & 7)] = f2b(o0[reg] * inv * g0);
            sX[lr * 128 + u1 * 8 + (lg & 7)] = f2b(o1[reg] * inv * g1);
        }
    }
    __syncthreads();

    // --- out-projection: wave h -> rows h*32 .. h*32+31
    bf16x8 a0[4], a1[4];
#pragma unroll
    for (int kc = 0; kc < 4; ++kc) {
        const int r0 = h * 32 + lg, r1 = h * 32 + 16 + lg;
        a0[kc] = *(const bf16x8*)(sX + r0 * 128 + (((kc * 4 + gr) ^ (r0 & 7)) << 3));
        a1[kc] = *(const bf16x8*)(sX + r1 * 128 + (((kc * 4 + gr) ^ (r1 & 7)) << 3));
    }
    const size_t prow = (size_t)rb + ihalf * 128 + h * 32;
    for (int nt = 0; nt < 8; ++nt) {
        bf16x8 bw[4];
#pragma unroll
        for (int kc = 0; kc < 4; ++kc)
            bw[kc] = *(const bf16x8*)(woT + (size_t)(nt * 16 + lg) * 128 + kc * 32 + gr * 8);
        f32x4 c0 = zero4, c1 = zero4;
#pragma unroll
        for (int kc = 0; kc < 4; ++kc) {
            c0 = __builtin_amdgcn_mfma_f32_16x16x32_bf16(a0[kc], bw[kc], c0, 0, 0, 0);
            c1 = __builtin_amdgcn_mfma_f32_16x16x32_bf16(a1[kc], bw[kc], c1, 0, 0, 0);
        }
        const int o = nt * 16 + lg;
        const float bo = b_out[o];
#pragma unroll
        for (int reg = 0; reg < 4; ++reg) {
            out[(prow + gr * 4 + reg) * 128 + o]      = c0[reg] + bo;
            out[(prow + 16 + gr * 4 + reg) * 128 + o] = c1[reg] + bo;
        }
    }
}

// ------------------------------------------------------------- launch
extern "C" void kernel_launch(void* const* d_in, const int* in_sizes, int n_in,
                              void* d_out, int out_size, void* d_ws, size_t ws_size,
                              hipStream_t stream)
{
    const float* z      = (const float*)d_in[0];
    const int*   smask  = (const int*)d_in[1];
    const float* ln_g   = (const float*)d_in[2];
    const float* ln_b   = (const float*)d_in[3];
    const float* w_qkv  = (const float*)d_in[4];
    const float* w_pair = (const float*)d_in[5];
    const float* w_gate = (const float*)d_in[6];
    const float* b_gate = (const float*)d_in[7];
    const float* w_out  = (const float*)d_in[8];
    const float* b_out  = (const float*)d_in[9];
    float* out = (float*)d_out;

    short* ws      = (short*)d_ws;
    short* qkb     = ws;                                   // 65536*256
    short* Vtb     = qkb + (size_t)NPOS * 256;             // 8388608
    short* wT      = Vtb + (size_t)8388608;                // 528*128
    short* woT     = wT + 528 * 128;                       // 128*128
    unsigned* mjbg = (unsigned*)(woT + 128 * 128);         // 16 u32 (8 used)
    short* pbb     = (short*)(mjbg + 16);                  // 4*65536
    short* gate_b  = pbb + (size_t)4 * NPOS;               // 65536*128

    k_prep<<<64, 256, 0, stream>>>(w_qkv, w_gate, w_pair, w_out, smask, wT, woT, mjbg);
    k_proj<<<NPOS / 64, 256, 0, stream>>>(z, ln_g, ln_b, wT, b_gate, qkb, Vtb, pbb, gate_b);
    k_attn<<<512, 256, 0, stream>>>(qkb, Vtb, pbb, smask, gate_b, mjbg, woT, b_out, out);
}